// Round 5
// baseline (239.058 us; speedup 1.0000x reference)
//
#include <hip/hip_runtime.h>
#include <cstddef>

namespace {

constexpr int kV = 4096;
constexpr int kBlocks = 8 * kV / 16;  // 2048 blocks, 16 v each

typedef float f32x16 __attribute__((ext_vector_type(16)));
typedef float f32x4  __attribute__((ext_vector_type(4)));
typedef short bf16x8 __attribute__((ext_vector_type(8)));

union U8 { unsigned u[4]; uint4 q; bf16x8 v; };

// round-to-nearest-even fp32->bf16, packed pair (a -> lo16, b -> hi16)
__device__ inline unsigned pk_bf16(float a, float b) {
    unsigned ua = __float_as_uint(a);
    unsigned ub = __float_as_uint(b);
    ua = (ua + 0x7FFFu + ((ua >> 16) & 1u)) >> 16;
    ub = (ub + 0x7FFFu + ((ub >> 16) & 1u)) & 0xFFFF0000u;
    return ua | ub;
}

// fp32 -> bf16 conversion of kernel_weights into d_ws (re-done every launch:
// d_ws is re-poisoned before each timed replay).
__global__ void convW(const float* __restrict__ W, unsigned* __restrict__ Wb) {
    const int i = blockIdx.x * 256 + threadIdx.x;   // 32768 = 65536/2
    const float2 w2 = ((const float2*)W)[i];
    Wb[i] = pk_bf16(w2.x, w2.y);
}

// Phase-1 k-slot permutation: MFMA pair pp <-> signal rows
// (8*(pp&3) + (pp>>2), +4). The p-contraction is permutation-invariant as
// long as A (ck) and B (signal) use the SAME sigma — lets each lane hold its
// k-pair in-register after dwordx4 row loads (concurrency fix, see R4 notes).
__global__ __launch_bounds__(256, 4)
void fused(const float* __restrict__ signal,
           const int* __restrict__ pidx_g,
           const float* __restrict__ ck_g,
           const unsigned short* __restrict__ Wb,   // bf16 weights from convW
           const float* __restrict__ bias,
           float* __restrict__ out)
{
    // zbf: phase-2 A operand, [g][j], j = c*8 + r*4 + l (pad 512->520 keeps
    // rows 16B-aligned). pS: per-WAVE staged signal, dword [pp][c] =
    // bf16{row sigma(2pp), row sigma(2pp+1)} at channel c. Wave-private ->
    // same-wave lgkmcnt ordering (compiler-inserted), NO per-vg barriers.
    __shared__ __align__(16) unsigned short zbf[16][520];   // 16.25 KB
    __shared__ __align__(16) unsigned pS[4][16][64];        // 16 KB

    const int t = threadIdx.x;
    const int b = blockIdx.x >> 8;
    const int v_base = (blockIdx.x & 255) * 16;
    const int w    = t >> 6;
    const int lane = t & 63;
    const int n31  = lane & 31;
    const int h    = lane >> 5;
    const int r4   = lane >> 4;     // row-quad (signal loads)
    const int cq   = lane & 15;     // channel-quad

    unsigned (*pSw)[64] = pS[w];
    const float* sgb = signal + (size_t)b * kV * 64;

    // Hoisted neighbor indices for all 4 wave-private v's (lane p holds vs_p).
    int vsl[4];
    #pragma unroll
    for (int vg = 0; vg < 4; ++vg)
        vsl[vg] = pidx_g[((((size_t)b * kV + v_base + vg * 4 + w) * 32) + n31) * 2 + 1];

    // ---------------- Phase 1: MFMA 32x32x16, D[m=rn][n=c] ----------------
    #pragma unroll
    for (int vg = 0; vg < 4; ++vg) {
        const int g = vg * 4 + w;                 // wave-private v
        const size_t bv = (size_t)b * kV + (v_base + g);
        const int vsv = vsl[vg];
        const float* ckv = ck_g + bv * 1024;      // [32 p][32 rn]

        // signal gather: 8 x dwordx4, 4 rows/instr (16 lanes x 16B per row)
        float4 S[8];
        #pragma unroll
        for (int k = 0; k < 8; ++k) {
            const int vs = __shfl(vsv, 4 * k + r4);
            S[k] = *(const float4*)(sgb + (size_t)vs * 64 + cq * 4);
        }
        // ck column n31, rows in sigma order (batched, no LDS in between)
        float cA[16];
        #pragma unroll
        for (int j2 = 0; j2 < 4; ++j2) {
            cA[4 * j2 + 0] = ckv[(8 * j2 + h    ) * 32 + n31];
            cA[4 * j2 + 1] = ckv[(8 * j2 + h + 4) * 32 + n31];
            cA[4 * j2 + 2] = ckv[(8 * j2 + h + 2) * 32 + n31];
            cA[4 * j2 + 3] = ckv[(8 * j2 + h + 6) * 32 + n31];
        }

        // stage signal as bf16 k-pairs: pS[pp = r4*4+m][c], b128 writes
        #pragma unroll
        for (int m = 0; m < 4; ++m) {
            uint4 d;
            d.x = pk_bf16(S[2 * m].x, S[2 * m + 1].x);
            d.y = pk_bf16(S[2 * m].y, S[2 * m + 1].y);
            d.z = pk_bf16(S[2 * m].z, S[2 * m + 1].z);
            d.w = pk_bf16(S[2 * m].w, S[2 * m + 1].w);
            *(uint4*)&pSw[r4 * 4 + m][cq * 4] = d;
        }

        // A-frags in-register: dword j2 = pair pp, A0: pp=4h+j2, A1: pp+8
        U8 A0, A1;
        #pragma unroll
        for (int j2 = 0; j2 < 4; ++j2) {
            A0.u[j2] = pk_bf16(cA[4 * j2 + 0], cA[4 * j2 + 1]);
            A1.u[j2] = pk_bf16(cA[4 * j2 + 2], cA[4 * j2 + 3]);
        }

        // B-frags from wave-private LDS (b32, bank=n31, 2-way = free)
        U8 B00, B01, B10, B11;
        #pragma unroll
        for (int j2 = 0; j2 < 4; ++j2) {
            B00.u[j2] = pSw[    4 * h + j2][n31];
            B01.u[j2] = pSw[    4 * h + j2][n31 + 32];
            B10.u[j2] = pSw[8 + 4 * h + j2][n31];
            B11.u[j2] = pSw[8 + 4 * h + j2][n31 + 32];
        }

        f32x16 acc0, acc1;
        #pragma unroll
        for (int j = 0; j < 16; ++j) { acc0[j] = 0.f; acc1[j] = 0.f; }
        acc0 = __builtin_amdgcn_mfma_f32_32x32x16_bf16(A0.v, B00.v, acc0, 0, 0, 0);
        acc1 = __builtin_amdgcn_mfma_f32_32x32x16_bf16(A0.v, B01.v, acc1, 0, 0, 0);
        acc0 = __builtin_amdgcn_mfma_f32_32x32x16_bf16(A1.v, B10.v, acc0, 0, 0, 0);
        acc1 = __builtin_amdgcn_mfma_f32_32x32x16_bf16(A1.v, B11.v, acc1, 0, 0, 0);

        // C-layout: col=lane&31 (=c), row=(reg&3)+8*(reg>>2)+4*h (=rn=r*16+n).
        #pragma unroll
        for (int ct = 0; ct < 2; ++ct) {
            const f32x16 a = ct ? acc1 : acc0;
            float s[16];
            #pragma unroll
            for (int j = 0; j < 16; ++j) s[j] = a[j] * a[j];
            // h=0 rows {0-3,8-11,16-19,24-27}; h=1 rows {4-7,12-15,20-23,28-31}
            const float o00 = s[0], o10 = s[1] + s[2] + s[3];
            const float o20 = s[4], o30 = s[5] + s[6] + s[7];
            const float o01 = s[8], o11 = s[9] + s[10] + s[11];
            const float o21 = s[12], o31 = s[13] + s[14] + s[15];
            const float x0 = s[0] + s[1] + s[2] + s[3];
            const float x1 = s[4] + s[5] + s[6] + s[7];
            const float x2 = s[8] + s[9] + s[10] + s[11];
            const float x3 = s[12] + s[13] + s[14] + s[15];
            const float e0 = __shfl_xor(h ? x0 : o20, 32);
            const float e1 = __shfl_xor(h ? x1 : o30, 32);
            const float e2 = __shfl_xor(h ? x2 : o21, 32);
            const float e3 = __shfl_xor(h ? x3 : o31, 32);
            if (h == 0) {
                const float z00 = sqrtf(fmaxf(o00,      1e-4f));
                const float z10 = sqrtf(fmaxf(o10,      1e-4f));
                const float z20 = sqrtf(fmaxf(o20 + e0, 1e-4f));
                const float z30 = sqrtf(fmaxf(o30 + e1, 1e-4f));
                const float z01 = sqrtf(fmaxf(o01,      1e-4f));
                const float z11 = sqrtf(fmaxf(o11,      1e-4f));
                const float z21 = sqrtf(fmaxf(o21 + e2, 1e-4f));
                const float z31 = sqrtf(fmaxf(o31 + e3, 1e-4f));
                uint4 d;
                d.x = pk_bf16(z00, z10);
                d.y = pk_bf16(z20, z30);
                d.z = pk_bf16(z01, z11);
                d.w = pk_bf16(z21, z31);
                *(uint4*)&zbf[g][(n31 + 32 * ct) * 8] = d;   // j = c*8+r*4+l
            }
        }
    }
    __syncthreads();   // zbf complete, visible to all waves (only barrier)

    // ------- Phase 2: MFMA 16x16x32, D[m=g][n=i], K=512, B = bf16 global ---
    const int m15 = lane & 15;          // A row g AND D col i
    const int q   = lane >> 4;          // k-quad
    f32x4 pa0, pa1;
    #pragma unroll
    for (int j = 0; j < 4; ++j) { pa0[j] = 0.f; pa1[j] = 0.f; }
    const int i0 = w * 32 + m15;
    const int i1 = w * 32 + 16 + m15;
    #pragma unroll 4
    for (int ks = 0; ks < 16; ++ks) {
        U8 Az, Bw0, Bw1;
        Az.q  = *(const uint4*)&zbf[m15][ks * 32 + q * 8];
        Bw0.q = *(const uint4*)&Wb[(size_t)i0 * 512 + ks * 32 + q * 8];
        Bw1.q = *(const uint4*)&Wb[(size_t)i1 * 512 + ks * 32 + q * 8];
        pa0 = __builtin_amdgcn_mfma_f32_16x16x32_bf16(Az.v, Bw0.v, pa0, 0, 0, 0);
        pa1 = __builtin_amdgcn_mfma_f32_16x16x32_bf16(Az.v, Bw1.v, pa1, 0, 0, 0);
    }
    const float bi0 = bias[i0], bi1 = bias[i1];
    #pragma unroll
    for (int reg = 0; reg < 4; ++reg) {
        const int g = q * 4 + reg;                       // D row = g
        const size_t row = ((size_t)b * kV + v_base + g) * 128;
        out[row + i0] = fmaxf(pa0[reg] + bi0, 0.f);
        out[row + i1] = fmaxf(pa1[reg] + bi1, 0.f);
    }
}

} // namespace

extern "C" void kernel_launch(void* const* d_in, const int* in_sizes, int n_in,
                              void* d_out, int out_size, void* d_ws, size_t ws_size,
                              hipStream_t stream) {
    const float* signal = (const float*)d_in[0];
    const int*   pidx   = (const int*)d_in[1];
    const float* ck     = (const float*)d_in[2];
    const float* W      = (const float*)d_in[3];
    const float* bias   = (const float*)d_in[4];
    float* out = (float*)d_out;
    unsigned* Wb = (unsigned*)d_ws;     // 128 KB bf16 weights

    convW<<<dim3(128), dim3(256), 0, stream>>>(W, Wb);
    fused<<<dim3(kBlocks), dim3(256), 0, stream>>>(
        signal, pidx, ck, (const unsigned short*)Wb, bias, out);
}